// Round 2
// baseline (103.250 us; speedup 1.0000x reference)
//
#include <hip/hip_runtime.h>

// Problem constants (fixed by reference)
#define BS      16
#define CIN     32
#define COUT    64
#define OUT_DIM 1024
#define DD      4096           // input spatial length

// out[b,o,p] = (1/sqrt(32)) * sum_{c,k} x[b,c,4p+k] * w[o,c,4p+k]
//
// v2: no LDS. x reuse across o-lanes is a same-address broadcast load (L1/L2
// serve it; x is 8 MB, L2-resident). Thread tile = 2b x 2o x 1p.
// Block = 4 patches x 32 o x 8 b = 1024 outputs, 256 threads.
// Grid = 1024 blocks = 256 patch-groups x {oh,bh}. 16 waves/CU (4 blocks/CU).
//
// XCD swizzle: xcd = bid>>7. Each XCD owns 32 consecutive patch groups and
// all 4 (oh,bh) siblings, so sibling x/w re-reads hit that XCD's L2 and the
// 4 blocks writing each 64B out line are co-located (full-line writeback).
__global__ __launch_bounds__(256, 4) void nolc1d_kernel(
    const float* __restrict__ x,
    const float* __restrict__ w,
    float* __restrict__ out)
{
    const int t   = threadIdx.x;
    const int bid = blockIdx.x;

    const int xcd = bid >> 7;        // 0..7
    const int i   = bid & 127;
    const int sub = i >> 5;          // 0..3
    const int gg  = xcd * 32 + (i & 31);   // patch group 0..255 (patches 4gg..4gg+3)
    const int oh  = sub & 1;
    const int bh  = sub >> 1;

    const int p_local = t & 3;          // patch within group (also float4 index)
    const int o_idx   = (t >> 2) & 15;
    const int bg      = t >> 6;         // wave id 0..3

    const int o0 = oh * 32 + o_idx * 2; // 2 consecutive o's
    const int b0 = bh * 8 + bg * 2;     // 2 consecutive b's

    const float4* __restrict__ x4 = (const float4*)x;
    const float4* __restrict__ w4 = (const float4*)w;

    const int rs = DD / 4;              // float4 per (.,c) row = 1024
    const size_t xbase0 = (size_t)b0 * (CIN * rs) + gg * 4 + p_local;
    const size_t xbase1 = xbase0 + (size_t)(CIN * rs);
    const size_t wbase0 = (size_t)o0 * (CIN * rs) + gg * 4 + p_local;
    const size_t wbase1 = wbase0 + (size_t)(CIN * rs);

    float a00 = 0.f, a01 = 0.f, a10 = 0.f, a11 = 0.f;

    #pragma unroll 4
    for (int c = 0; c < CIN; ++c) {
        // w: 16 o-lanes x 4 p-lanes -> 16 full 64B segments per instruction.
        float4 wv0 = w4[wbase0 + (size_t)c * rs];
        float4 wv1 = w4[wbase1 + (size_t)c * rs];
        // x: 16-way same-address broadcast across o-lanes (4 distinct 16B addrs).
        float4 xv0 = x4[xbase0 + (size_t)c * rs];
        float4 xv1 = x4[xbase1 + (size_t)c * rs];

        a00 += xv0.x * wv0.x + xv0.y * wv0.y + xv0.z * wv0.z + xv0.w * wv0.w;
        a01 += xv0.x * wv1.x + xv0.y * wv1.y + xv0.z * wv1.z + xv0.w * wv1.w;
        a10 += xv1.x * wv0.x + xv1.y * wv0.y + xv1.z * wv0.z + xv1.w * wv0.w;
        a11 += xv1.x * wv1.x + xv1.y * wv1.y + xv1.z * wv1.z + xv1.w * wv1.w;
    }

    const float scale = 0.17677669529663687f;  // 1/sqrt(32)
    const int pg = gg * 4 + p_local;
    out[((size_t)b0       * COUT + o0    ) * OUT_DIM + pg] = a00 * scale;
    out[((size_t)b0       * COUT + o0 + 1) * OUT_DIM + pg] = a01 * scale;
    out[((size_t)(b0 + 1) * COUT + o0    ) * OUT_DIM + pg] = a10 * scale;
    out[((size_t)(b0 + 1) * COUT + o0 + 1) * OUT_DIM + pg] = a11 * scale;
}

extern "C" void kernel_launch(void* const* d_in, const int* in_sizes, int n_in,
                              void* d_out, int out_size, void* d_ws, size_t ws_size,
                              hipStream_t stream) {
    const float* x = (const float*)d_in[0];   // [16][32][4096] fp32
    const float* w = (const float*)d_in[1];   // [64][32][4096] fp32
    float* out = (float*)d_out;               // [16][64][1024] fp32

    nolc1d_kernel<<<dim3(1024), dim3(256), 0, stream>>>(x, w, out);
}

// Round 3
// 89.142 us; speedup vs baseline: 1.1583x; 1.1583x over previous
//
#include <hip/hip_runtime.h>

// Problem constants (fixed by reference)
#define BS      16
#define CIN     32
#define COUT    64
#define OUT_DIM 1024
#define DD      4096           // input spatial length

// Tiling
#define OT      4              // o per block
#define PT      64             // patches per block -> d-span 256 floats = 1 KB rows
#define CCH     8              // c-chunk (double-buffered w staging)
#define NCH     (CIN / CCH)    // 4 chunks

// out[b,o,p] = (1/sqrt(32)) * sum_{c,k} x[b,c,4p+k] * w[o,c,4p+k]
//
// v3: DRAM-pattern-first design. Every global stream is 1 KB contiguous:
//   - w[o][c][d0..d0+255] rows staged to LDS (each row = 64 lanes x 16 B),
//     double-buffered in chunks of 8 c (2 x 32 KB LDS) so the 32 MB w stream
//     overlaps compute. Each w row is fetched exactly once per block.
//   - x[b][c][d0..d0+255] rows read from global, one wave per (b-pair),
//     each row read exactly once per block.
//   - out rows: 64 lanes x 4 B = 256 B contiguous, 64-aligned -> full-line
//     writes, single writer per line (fixes v2's 2x write amplification).
// Grid = 256 blocks (16 o-groups x 16 p-groups), 512 threads (8 waves).
// XCD swizzle: real mapping is bid % 8 -> XCD. bid = (pg&7) + 8*(og + 16*(pg>>3))
// puts all 16 og-blocks sharing an x chunk on one XCD (x served from its L2).
__global__ __launch_bounds__(512, 2) void nolc1d_kernel(
    const float* __restrict__ x,
    const float* __restrict__ w,
    float* __restrict__ out)
{
    const int bid = blockIdx.x;
    const int xcd = bid & 7;
    const int j   = bid >> 3;
    const int og  = j & 15;                 // o-group 0..15
    const int pg  = xcd + 8 * (j >> 4);     // patch-group 0..15
    const int o0  = og * OT;
    const int p0  = pg * PT;                // patch base; float4 row offset = p0

    const int t    = threadIdx.x;
    const int lane = t & 63;
    const int wv   = t >> 6;                // wave 0..7
    const int b0   = wv * 2;                // this wave's b-pair

    // [buf][ (c_in*OT + o_in) * 64 + lane ] ; 2 x 32 KB
    __shared__ float4 ws4[2][CCH * OT * 64];

    const float4* __restrict__ x4 = (const float4*)x;
    const float4* __restrict__ w4 = (const float4*)w;
    const int rs = DD / 4;                  // float4 per (.,c) row = 1024

    // Stage one c-chunk of w into LDS buffer `buf`.
    // 32 rows (8 c x 4 o) of 1 KB; 4 rows per wave; 64 lanes x 16 B per row.
    auto stage = [&](int buf, int ch) {
        #pragma unroll
        for (int i = 0; i < 4; ++i) {
            const int r    = wv * 4 + i;    // 0..31
            const int c_in = r >> 2;        // 0..7
            const int o_in = r & 3;         // 0..3
            const int c    = ch * CCH + c_in;
            ws4[buf][r * 64 + lane] =
                w4[((size_t)(o0 + o_in) * CIN + c) * rs + p0 + lane];
        }
    };

    float acc[2][OT] = {};

    stage(0, 0);
    __syncthreads();

    for (int ch = 0; ch < NCH; ++ch) {
        if (ch + 1 < NCH) stage((ch + 1) & 1, ch + 1);  // fill other buffer
        const int buf = ch & 1;

        #pragma unroll
        for (int ci = 0; ci < CCH; ++ci) {
            const int c = ch * CCH + ci;
            // x rows: 1 KB contiguous per (b,c); each row read by exactly 1 wave
            const float4 xv0 = x4[((size_t)b0       * CIN + c) * rs + p0 + lane];
            const float4 xv1 = x4[((size_t)(b0 + 1) * CIN + c) * rs + p0 + lane];
            #pragma unroll
            for (int o = 0; o < OT; ++o) {
                const float4 wvv = ws4[buf][(ci * OT + o) * 64 + lane];
                acc[0][o] += xv0.x * wvv.x + xv0.y * wvv.y +
                             xv0.z * wvv.z + xv0.w * wvv.w;
                acc[1][o] += xv1.x * wvv.x + xv1.y * wvv.y +
                             xv1.z * wvv.z + xv1.w * wvv.w;
            }
        }
        __syncthreads();  // readers done with buf AND next stage visible
    }

    const float scale = 0.17677669529663687f;  // 1/sqrt(32)
    #pragma unroll
    for (int bi = 0; bi < 2; ++bi) {
        #pragma unroll
        for (int o = 0; o < OT; ++o) {
            out[((size_t)(b0 + bi) * COUT + (o0 + o)) * OUT_DIM + p0 + lane] =
                acc[bi][o] * scale;
        }
    }
}

extern "C" void kernel_launch(void* const* d_in, const int* in_sizes, int n_in,
                              void* d_out, int out_size, void* d_ws, size_t ws_size,
                              hipStream_t stream) {
    const float* x = (const float*)d_in[0];   // [16][32][4096] fp32
    const float* w = (const float*)d_in[1];   // [64][32][4096] fp32
    float* out = (float*)d_out;               // [16][64][1024] fp32

    nolc1d_kernel<<<dim3(256), dim3(512), 0, stream>>>(x, w, out);
}